// Round 19
// baseline (684.446 us; speedup 1.0000x reference)
//
#include <hip/hip_runtime.h>
#include <hip/hip_fp16.h>

#define Nn 50000
#define Ee 800000
#define FIN 32
#define EDIM 16
#define Bb 50
#define SPX 6250   // 16-edge spans per XCD (50000 total / 8)

typedef _Float16 half8 __attribute__((ext_vector_type(8)));
typedef float floatx4 __attribute__((ext_vector_type(4)));

// wT (f16 transposed weights) offsets, in f16 elements
#define OFF_WeT 0
#define WT_LAYER(l) (3072 + (l) * 58368)
#define OFF_W1AB 0        // [192][96]
#define OFF_W1C  18432    // [96][32]
#define OFF_W2   21504    // [96][96]
#define OFF_NW1  30720    // [96][192]
#define OFF_NW2  49152    // [96][96]
#define WT_TOTAL 178176

// f16-native silu: v_exp_f16/v_rcp_f16, no f32 converts
__device__ __forceinline__ _Float16 silu_h32(float xf) {
    __half x = __float2half(xf);
    __half e = hexp(__hneg(x));
    __half r = hrcp(__hadd(__float2half(1.0f), e));
    __half res = __hmul(x, r);
    return __builtin_bit_cast(_Float16, res);
}

__device__ __forceinline__ half8 silu_h8(half8 v) {
    half8 out;
    __half2* vp = (__half2*)&v;
    __half2* op = (__half2*)&out;
    const __half2 one = __float2half2_rn(1.0f);
    #pragma unroll
    for (int i = 0; i < 4; i++) {
        __half2 x = vp[i];
        __half2 e = h2exp(__hneg2(x));
        __half2 r = h2rcp(__hadd2(one, e));
        op[i] = __hmul2(x, r);
    }
    return out;
}

__device__ __forceinline__ int lower_bound_i(const int* a, int n, int v) {
    int lo = 0, hi = n;
    while (lo < hi) { int m = (lo + hi) >> 1; if (a[m] < v) lo = m + 1; else hi = m; }
    return lo;
}

__device__ __forceinline__ half8 ldg_h8(const _Float16* p) {
    return *(const half8*)p;
}

__device__ __forceinline__ half8 h8_zero() {
    half8 z;
    #pragma unroll
    for (int j = 0; j < 8; j++) z[j] = (_Float16)0.f;
    return z;
}

// ---------------- weight transpose+cast to f16 ----------------
__global__ void k_prepw(const float* __restrict__ We, const float* __restrict__ eW1,
                        const float* __restrict__ eW2, const float* __restrict__ nW1,
                        const float* __restrict__ nW2, _Float16* __restrict__ wT) {
    int idx = blockIdx.x * 256 + threadIdx.x;
    if (idx >= WT_TOTAL) return;
    float v;
    if (idx < 3072) {                       // WeT[n][k]
        int n = idx >> 5, k = idx & 31;
        v = We[k * 96 + n];
    } else {
        int j = idx - 3072;
        int l = j / 58368, r = j % 58368;
        const float* eW1l = eW1 + l * 209 * 96;
        if (r < 18432) {                    // W1abT[n][k]
            int n = r / 96, k = r % 96;
            v = (n < 96) ? eW1l[k * 96 + n] : eW1l[(96 + k) * 96 + (n - 96)];
        } else if (r < 21504) {             // W1cT[n][k]
            int r2 = r - 18432;
            int n = r2 >> 5, k = r2 & 31;
            v = (k < 16) ? eW1l[(193 + k) * 96 + n]
              : (k == 16) ? eW1l[192 * 96 + n] : 0.f;
        } else if (r < 30720) {             // W2T[n][k]
            int r2 = r - 21504;
            int n = r2 / 96, k = r2 % 96;
            v = eW2[l * 9216 + k * 96 + n];
        } else if (r < 49152) {             // nW1T[n][k]
            int r2 = r - 30720;
            int n = r2 / 192, k = r2 % 192;
            v = nW1[l * 18432 + k * 96 + n];
        } else {                            // nW2T[n][k]
            int r2 = r - 49152;
            int n = r2 / 96, k = r2 % 96;
            v = nW2[l * 9216 + k * 96 + n];
        }
    }
    wT[idx] = (_Float16)v;
}

// ---------------- edge prep: dst histogram only ----------------
__global__ void k_prep(const int* __restrict__ ei, int* __restrict__ counts) {
    int e = blockIdx.x * 256 + threadIdx.x;
    if (e >= Ee) return;
    atomicAdd(&counts[ei[Ee + e]], 1);
}

// ---------------- two-level exclusive scan -> rowstart ----------------
__global__ void k_scanA(const int* __restrict__ counts, int* __restrict__ rowstart,
                        int* __restrict__ bsums) {
    __shared__ int s[256];
    int b = blockIdx.x, t = threadIdx.x, i = b * 256 + t;
    int v = (i < Nn) ? counts[i] : 0;
    s[t] = v;
    __syncthreads();
    for (int off = 1; off < 256; off <<= 1) {
        int add = (t >= off) ? s[t - off] : 0;
        __syncthreads();
        s[t] += add;
        __syncthreads();
    }
    if (i < Nn) rowstart[i + 1] = s[t];
    if (t == 255) bsums[b] = s[255];
}

__global__ void k_scanB(int* __restrict__ bsums, int nb) {
    __shared__ int s[256];
    int t = threadIdx.x;
    int v = (t < nb) ? bsums[t] : 0;
    s[t] = v;
    __syncthreads();
    for (int off = 1; off < 256; off <<= 1) {
        int add = (t >= off) ? s[t - off] : 0;
        __syncthreads();
        s[t] += add;
        __syncthreads();
    }
    if (t < nb) bsums[t] = s[t] - v;
}

__global__ void k_scanC(int* __restrict__ rowstart, const int* __restrict__ bsums) {
    int b = blockIdx.x, t = threadIdx.x, i = b * 256 + t;
    if (i < Nn) rowstart[i + 1] += bsums[b];
    if (i == 0 && b == 0) rowstart[0] = 0;
}

// ---------------- CSR fill pass 1: scatter perm only (4 B/edge) ----------------
__global__ void k_fill1(const int* __restrict__ ei, const int* __restrict__ rowstart,
                        int* __restrict__ cur, int* __restrict__ perm) {
    int e = blockIdx.x * 256 + threadIdx.x;
    if (e >= Ee) return;
    int d = ei[Ee + e];
    int slot = rowstart[d] + atomicAdd(&cur[d], 1);
    perm[slot] = e;
}

// ---------------- CSR fill pass 2: gather (random reads), coalesced writes -----
__global__ void k_fill2(const int* __restrict__ perm, const int* __restrict__ ei,
                        const float* __restrict__ ea, const float* __restrict__ pos,
                        int* __restrict__ srcs_p, int* __restrict__ dsts_p,
                        _Float16* __restrict__ eap16, _Float16* __restrict__ d2h) {
    int slot = blockIdx.x * 256 + threadIdx.x;
    if (slot >= Ee) return;
    int e = perm[slot];
    int s = ei[e], d = ei[Ee + e];
    srcs_p[slot] = s;
    dsts_p[slot] = d;
    float dx = pos[s * 3 + 0] - pos[d * 3 + 0];
    float dy = pos[s * 3 + 1] - pos[d * 3 + 1];
    float dz = pos[s * 3 + 2] - pos[d * 3 + 2];
    float dv = dx * dx + dy * dy + dz * dz;
    const float4* ea4 = (const float4*)ea;
    float4 q0 = ea4[e * 4 + 0], q1 = ea4[e * 4 + 1];
    float4 q2 = ea4[e * 4 + 2], q3 = ea4[e * 4 + 3];
    half8 c0, c1;
    c0[0]=(_Float16)q0.x; c0[1]=(_Float16)q0.y; c0[2]=(_Float16)q0.z; c0[3]=(_Float16)q0.w;
    c0[4]=(_Float16)q1.x; c0[5]=(_Float16)q1.y; c0[6]=(_Float16)q1.z; c0[7]=(_Float16)q1.w;
    c1[0]=(_Float16)q2.x; c1[1]=(_Float16)q2.y; c1[2]=(_Float16)q2.z; c1[3]=(_Float16)q2.w;
    c1[4]=(_Float16)q3.x; c1[5]=(_Float16)q3.y; c1[6]=(_Float16)q3.z; c1[7]=(_Float16)q3.w;
    half8* dst8 = (half8*)(eap16 + (size_t)slot * 16);
    dst8[0] = c0; dst8[1] = c1;
    d2h[slot] = (_Float16)dv;
}

// ---------------- encoder + A/B(l0) + zero agg (f16) ----------------
__global__ __launch_bounds__(256, 4)
void k_encab(const float* __restrict__ x, const _Float16* __restrict__ WeT,
             const float* __restrict__ be, const _Float16* __restrict__ W1abT,
             _Float16* __restrict__ h16, _Float16* __restrict__ A16,
             _Float16* __restrict__ B16, _Float16* __restrict__ agg16) {
    __shared__ _Float16 x16[64][40];
    __shared__ _Float16 hs[64][104];
    int t = threadIdx.x;
    int n0 = blockIdx.x * 64;
    for (int i = t; i < 64 * 32; i += 256) {
        int nl = i >> 5, k = i & 31;
        int n = n0 + nl;
        x16[nl][k] = (_Float16)((n < Nn) ? x[n * FIN + k] : 0.f);
    }
    __syncthreads();
    int lane = t & 63, quad = lane >> 4, lm = lane & 15, w = t >> 6;
    half8 af = *(const half8*)&x16[w * 16 + lm][quad * 8];
    #pragma unroll
    for (int nt = 0; nt < 6; nt++) {
        int col = nt * 16 + lm;
        float b = be[col];
        floatx4 acc = {b, b, b, b};
        half8 bf = ldg_h8(WeT + col * 32 + quad * 8);
        acc = __builtin_amdgcn_mfma_f32_16x16x32_f16(af, bf, acc, 0, 0, 0);
        #pragma unroll
        for (int r = 0; r < 4; r++)
            hs[w * 16 + quad * 4 + r][col] = (_Float16)acc[r];
    }
    __syncthreads();
    // coalesced h16 write + zero agg (f16)
    #pragma unroll
    for (int i = 0; i < 3; i++) {
        int ci = t + 256 * i;
        int el = ci / 12, c0 = (ci % 12) * 8;
        int n = n0 + el;
        if (n < Nn) {
            *(half8*)(h16 + n * 96 + c0) = *(half8*)&hs[el][c0];
            *(half8*)(agg16 + n * 96 + c0) = h8_zero();
        }
    }
    // A/B for layer 0
    half8 af3[3];
    #pragma unroll
    for (int kt = 0; kt < 3; kt++)
        af3[kt] = *(const half8*)&hs[w * 16 + lm][kt * 32 + quad * 8];
    #pragma unroll
    for (int nt = 0; nt < 12; nt++) {
        int col = nt * 16 + lm;
        floatx4 acc = {0.f, 0.f, 0.f, 0.f};
        #pragma unroll
        for (int kt = 0; kt < 3; kt++) {
            half8 bf = ldg_h8(W1abT + col * 96 + kt * 32 + quad * 8);
            acc = __builtin_amdgcn_mfma_f32_16x16x32_f16(af3[kt], bf, acc, 0, 0, 0);
        }
        #pragma unroll
        for (int r = 0; r < 4; r++) {
            int n = n0 + w * 16 + quad * 4 + r;
            if (n < Nn) {
                if (col < 96) A16[n * 96 + col] = (_Float16)acc[r];
                else          B16[n * 96 + col - 96] = (_Float16)acc[r];
            }
        }
    }
}

// ---------------- per-layer edge kernel: wave-autonomous, 5 blocks/CU ----------
// LDS: u16 13312 + W2f 18432 + ss/ds 512 = 32256 B <= 32768 -> 5 blocks/CU.
// W1c fragments in registers (24 VGPRs); __launch_bounds__ stays (256,4) so the
// compiler's VGPR cap is NOT crushed (r7/r12 lesson: the spills came from the
// bound, not the hoist). Occupancy rises via the LDS limit only.
__global__ __launch_bounds__(256, 4)
void k_edge(const _Float16* __restrict__ A16, const _Float16* __restrict__ B16,
            const _Float16* __restrict__ eap16, const _Float16* __restrict__ d2h,
            const int* __restrict__ srcs_p, const int* __restrict__ dsts_p,
            const _Float16* __restrict__ W1cT, const float* __restrict__ eb1l,
            const _Float16* __restrict__ W2T, const float* __restrict__ eb2l,
            _Float16* __restrict__ agg16) {
    __shared__ _Float16 u16[64][104];       // wave-private 16-row quarters
    __shared__ _Float16 W2f[18 * 64 * 8];   // fragment-major: [nt*3+kt][lane][8]
    __shared__ int ss_s[4][16], ds_s[4][16];

    int t = threadIdx.x;
    int lane = t & 63, quad = lane >> 4, lm = lane & 15, w = t >> 6;

    // one-time fragment-major W2 staging
    for (int f = w; f < 18; f += 4) {
        int nt = f / 3, kt = f % 3;
        half8 v = ldg_h8(W2T + (nt * 16 + lm) * 96 + kt * 32 + quad * 8);
        *(half8*)&W2f[(f * 64 + lane) * 8] = v;
    }
    // W1c fragments: loop-invariant registers
    half8 w1f[6];
    #pragma unroll
    for (int nt = 0; nt < 6; nt++)
        w1f[nt] = ldg_h8(W1cT + (nt * 16 + lm) * 32 + quad * 8);
    float eb1v[6], eb2v[6];
    #pragma unroll
    for (int nt = 0; nt < 6; nt++) {
        eb1v[nt] = eb1l[nt * 16 + lm];
        eb2v[nt] = eb2l[nt * 16 + lm];
    }
    __syncthreads();   // the only barrier

    int xcd = blockIdx.x & 7, ib = blockIdx.x >> 3;   // 160 blocks/XCD
    int slot = ib * 4 + w;                            // 640 wave slots per XCD
    for (int s = slot; s < SPX; s += 640) {
        int e0 = (xcd * SPX + s) * 16;
        // ---- prefetch edge data (global only) ----
        half8 af1;
        if (quad == 0)      af1 = ldg_h8(eap16 + (size_t)(e0 + lm) * 16);
        else if (quad == 1) af1 = ldg_h8(eap16 + (size_t)(e0 + lm) * 16 + 8);
        else { af1 = h8_zero(); if (quad == 2) af1[0] = d2h[e0 + lm]; }
        if (lane < 16) {
            ss_s[w][lane] = srcs_p[e0 + lane];
            ds_s[w][lane] = dsts_p[e0 + lane];
        }
        // ---- phase 1a: pre = eb1 + [ea|d2]@W1c -> u16 (C-layout, own rows) ----
        #pragma unroll
        for (int nt = 0; nt < 6; nt++) {
            floatx4 acc = {eb1v[nt], eb1v[nt], eb1v[nt], eb1v[nt]};
            acc = __builtin_amdgcn_mfma_f32_16x16x32_f16(af1, w1f[nt], acc, 0, 0, 0);
            #pragma unroll
            for (int r = 0; r < 4; r++)
                u16[w * 16 + quad * 4 + r][nt * 16 + lm] = (_Float16)acc[r];
        }
        // ---- phase 1b: u = silu(pre + A[src] + B[dst]); packed f16 silu ----
        #pragma unroll
        for (int i = 0; i < 3; i++) {
            int ci = lane + 64 * i;          // 192 chunks = 16 rows x 12
            int el = ci / 12, c0 = (ci % 12) * 8;
            half8 av = ldg_h8(A16 + ss_s[w][el] * 96 + c0);
            half8 bv = ldg_h8(B16 + ds_s[w][el] * 96 + c0);
            half8 pv = *(half8*)&u16[w * 16 + el][c0];
            *(half8*)&u16[w * 16 + el][c0] = silu_h8(pv + av + bv);
        }
        // ---- phase 2: m = silu(u @ W2 + eb2) -> u16 (own rows) ----
        half8 af2[3];
        #pragma unroll
        for (int kt = 0; kt < 3; kt++)
            af2[kt] = *(const half8*)&u16[w * 16 + lm][kt * 32 + quad * 8];
        #pragma unroll
        for (int nt = 0; nt < 6; nt++) {
            floatx4 acc = {eb2v[nt], eb2v[nt], eb2v[nt], eb2v[nt]};
            #pragma unroll
            for (int kt = 0; kt < 3; kt++) {
                half8 bf = *(const half8*)&W2f[((nt * 3 + kt) * 64 + lane) * 8];
                acc = __builtin_amdgcn_mfma_f32_16x16x32_f16(af2[kt], bf, acc, 0, 0, 0);
            }
            #pragma unroll
            for (int r = 0; r < 4; r++)
                u16[w * 16 + quad * 4 + r][nt * 16 + lm] = silu_h32(acc[r]);
        }
        // ---- segmented reduction: 48-lane column-pair scan, packed atomics ----
        if (lane < 48) {
            __half2* aggp = (__half2*)agg16;
            float run0 = 0.f, run1 = 0.f;
            int cd = ds_s[w][0];
            #pragma unroll
            for (int e = 0; e < 16; e++) {
                int dn = ds_s[w][e];
                if (dn != cd) {
                    unsafeAtomicAdd(&aggp[cd * 48 + lane], __floats2half2_rn(run0, run1));
                    run0 = 0.f; run1 = 0.f; cd = dn;
                }
                __half2 v = *(const __half2*)&u16[w * 16 + e][lane * 2];
                float2 vf = __half22float2(v);
                run0 += vf.x; run1 += vf.y;
            }
            unsafeAtomicAdd(&aggp[cd * 48 + lane], __floats2half2_rn(run0, run1));
        }
    }
}

// ---------------- node MLP + residual + next-layer A/B (or fused pooling) -----
__global__ __launch_bounds__(256, 4)
void k_nodeab(_Float16* __restrict__ h16, _Float16* __restrict__ agg16,
              const _Float16* __restrict__ nW1T, const float* __restrict__ nb1l,
              const _Float16* __restrict__ nW2T, const float* __restrict__ nb2l,
              const _Float16* __restrict__ W1abT, _Float16* __restrict__ A16,
              _Float16* __restrict__ B16, const int* __restrict__ batch,
              float* __restrict__ pooled, int do_ab) {
    __shared__ _Float16 in16[64][200];   // [h | agg] f16
    __shared__ _Float16 t116[64][104];
    __shared__ int gb_s[64];
    int t = threadIdx.x, n0 = blockIdx.x * 64;
    #pragma unroll
    for (int i = 0; i < 3; i++) {
        int ci = t + 256 * i;
        int el = ci / 12, c0 = (ci % 12) * 8;
        int n = n0 + el;
        half8 hv = h8_zero();
        half8 av = h8_zero();
        if (n < Nn) {
            hv = ldg_h8(h16 + n * 96 + c0);
            av = ldg_h8(agg16 + n * 96 + c0);
        }
        *(half8*)&in16[el][c0] = hv;
        *(half8*)&in16[el][96 + c0] = av;
    }
    if (!do_ab && t < 64) {
        int n = n0 + t;
        gb_s[t] = (n < Nn) ? batch[n] : -1;
    }
    __syncthreads();
    int lane = t & 63, quad = lane >> 4, lm = lane & 15, w = t >> 6;
    half8 af[6];
    #pragma unroll
    for (int kt = 0; kt < 6; kt++)
        af[kt] = *(const half8*)&in16[w * 16 + lm][kt * 32 + quad * 8];
    #pragma unroll
    for (int nt = 0; nt < 6; nt++) {
        int col = nt * 16 + lm;
        float b = nb1l[col];
        floatx4 acc = {b, b, b, b};
        #pragma unroll
        for (int kt = 0; kt < 6; kt++) {
            half8 bf = ldg_h8(nW1T + col * 192 + kt * 32 + quad * 8);
            acc = __builtin_amdgcn_mfma_f32_16x16x32_f16(af[kt], bf, acc, 0, 0, 0);
        }
        #pragma unroll
        for (int r = 0; r < 4; r++)
            t116[w * 16 + quad * 4 + r][col] = silu_h32(acc[r]);
    }
    // t116 rows are wave-private: same-wave LDS ops are ordered -> no barrier.
    half8 af2[3];
    #pragma unroll
    for (int kt = 0; kt < 3; kt++)
        af2[kt] = *(const half8*)&t116[w * 16 + lm][kt * 32 + quad * 8];
    #pragma unroll
    for (int nt = 0; nt < 6; nt++) {
        int col = nt * 16 + lm;
        float b = nb2l[col];
        floatx4 acc = {b, b, b, b};
        #pragma unroll
        for (int kt = 0; kt < 3; kt++) {
            half8 bf = ldg_h8(nW2T + col * 96 + kt * 32 + quad * 8);
            acc = __builtin_amdgcn_mfma_f32_16x16x32_f16(af2[kt], bf, acc, 0, 0, 0);
        }
        // residual: h_new = h_old + upd (same owner thread)
        #pragma unroll
        for (int r = 0; r < 4; r++) {
            int row = w * 16 + quad * 4 + r;
            float hnew = (float)in16[row][col] + acc[r];
            in16[row][col] = (_Float16)hnew;
        }
    }
    __syncthreads();   // in16 read cross-wave below
    if (!do_ab) {
        // fused global_mean_pool numerator: segmented scan by graph id.
        if (t < 96) {
            float run = 0.f;
            int cd = gb_s[0];
            for (int e = 0; e < 64; e++) {
                int g = gb_s[e];
                if (g != cd) {
                    if (cd >= 0) atomicAdd(&pooled[cd * 96 + t], run);
                    run = 0.f; cd = g;
                }
                run += (float)in16[e][t];
            }
            if (cd >= 0) atomicAdd(&pooled[cd * 96 + t], run);
        }
        return;
    }
    // coalesced h16 write + next-layer A/B + agg rezero (f16)
    #pragma unroll
    for (int i = 0; i < 3; i++) {
        int ci = t + 256 * i;
        int el = ci / 12, c0 = (ci % 12) * 8;
        int n = n0 + el;
        if (n < Nn) {
            *(half8*)(h16 + n * 96 + c0) = *(half8*)&in16[el][c0];
            *(half8*)(agg16 + n * 96 + c0) = h8_zero();
        }
    }
    half8 af3[3];
    #pragma unroll
    for (int kt = 0; kt < 3; kt++)
        af3[kt] = *(const half8*)&in16[w * 16 + lm][kt * 32 + quad * 8];
    #pragma unroll
    for (int nt = 0; nt < 12; nt++) {
        int col = nt * 16 + lm;
        floatx4 acc = {0.f, 0.f, 0.f, 0.f};
        #pragma unroll
        for (int kt = 0; kt < 3; kt++) {
            half8 bf = ldg_h8(W1abT + col * 96 + kt * 32 + quad * 8);
            acc = __builtin_amdgcn_mfma_f32_16x16x32_f16(af3[kt], bf, acc, 0, 0, 0);
        }
        #pragma unroll
        for (int r = 0; r < 4; r++) {
            int n = n0 + w * 16 + quad * 4 + r;
            if (n < Nn) {
                if (col < 96) A16[n * 96 + col] = (_Float16)acc[r];
                else          B16[n * 96 + col - 96] = (_Float16)acc[r];
            }
        }
    }
}

// ---------------- final head ----------------
__global__ void k_final(const float* __restrict__ pooled, const int* __restrict__ batch,
                        const float* __restrict__ Wl, const float* __restrict__ bl,
                        float* __restrict__ out) {
    int g = blockIdx.x, lane = threadIdx.x;
    int start = lower_bound_i(batch, Nn, g);
    int end   = lower_bound_i(batch, Nn, g + 1);
    int cnt = end - start; if (cnt < 1) cnt = 1;
    float v = 0.f;
    for (int j = lane; j < 96; j += 64) v += pooled[g * 96 + j] * Wl[j];
    #pragma unroll
    for (int off = 32; off > 0; off >>= 1) v += __shfl_down(v, off);
    if (lane == 0) out[g] = v / (float)cnt + bl[0];
}

extern "C" void kernel_launch(void* const* d_in, const int* in_sizes, int n_in,
                              void* d_out, int out_size, void* d_ws, size_t ws_size,
                              hipStream_t stream) {
    const float* x     = (const float*)d_in[0];
    const float* pos   = (const float*)d_in[1];
    const int*   ei    = (const int*)d_in[2];
    const float* ea    = (const float*)d_in[3];
    const int*   batch = (const int*)d_in[4];
    const float* We    = (const float*)d_in[5];
    const float* be    = (const float*)d_in[6];
    const float* eW1   = (const float*)d_in[7];
    const float* eb1   = (const float*)d_in[8];
    const float* eW2   = (const float*)d_in[9];
    const float* eb2   = (const float*)d_in[10];
    const float* nW1   = (const float*)d_in[11];
    const float* nb1   = (const float*)d_in[12];
    const float* nW2   = (const float*)d_in[13];
    const float* nb2   = (const float*)d_in[14];
    const float* Wl    = (const float*)d_in[15];
    const float* bl    = (const float*)d_in[16];
    float* out = (float*)d_out;

    float* ws = (float*)d_ws;
    _Float16* h16    = (_Float16*)(ws);                 // 4.8M halfs
    _Float16* A16    = (_Float16*)(ws + 2400000);       // 4.8M halfs
    _Float16* B16    = (_Float16*)(ws + 4800000);       // 4.8M halfs
    _Float16* agg16  = (_Float16*)(ws + 7200000);       // 4.8M halfs
    float*    pooled = ws + 9600000;                    // 4800
    int*      counts   = (int*)(ws + 9604800);          // 50000
    int*      cur      = (int*)(ws + 9654800);          // 50000
    int*      rowstart = (int*)(ws + 9704800);          // 50001
    int*      bsums    = (int*)(ws + 9754816);          // 256
    int*      srcs_p   = (int*)(ws + 9755072);          // 800000
    int*      dsts_p   = (int*)(ws + 10555072);         // 800000
    int*      perm     = (int*)(ws + 11355072);         // 800000
    _Float16* eap16    = (_Float16*)(ws + 12155072);    // 12.8M halfs
    _Float16* d2h      = (_Float16*)(ws + 18555072);    // 0.8M halfs
    _Float16* wT       = (_Float16*)(ws + 18955072);    // 178176 halfs

    hipMemsetAsync(counts, 0, 2 * 50000 * sizeof(int), stream);   // counts + cur
    hipMemsetAsync(pooled, 0, Bb * 96 * sizeof(float), stream);

    k_prepw<<<dim3(696), dim3(256), 0, stream>>>(We, eW1, eW2, nW1, nW2, wT);
    k_prep<<<dim3(3125), dim3(256), 0, stream>>>(ei, counts);
    k_scanA<<<dim3(196), dim3(256), 0, stream>>>(counts, rowstart, bsums);
    k_scanB<<<dim3(1), dim3(256), 0, stream>>>(bsums, 196);
    k_scanC<<<dim3(196), dim3(256), 0, stream>>>(rowstart, bsums);
    k_fill1<<<dim3(3125), dim3(256), 0, stream>>>(ei, rowstart, cur, perm);
    k_fill2<<<dim3(3125), dim3(256), 0, stream>>>(perm, ei, ea, pos,
                                                  srcs_p, dsts_p, eap16, d2h);
    k_encab<<<dim3(782), dim3(256), 0, stream>>>(x, wT + OFF_WeT, be,
        wT + WT_LAYER(0) + OFF_W1AB, h16, A16, B16, agg16);

    for (int l = 0; l < 3; l++) {
        const _Float16* wl = wT + WT_LAYER(l);
        k_edge<<<dim3(1280), dim3(256), 0, stream>>>(A16, B16, eap16, d2h,
            srcs_p, dsts_p, wl + OFF_W1C, eb1 + l * 96, wl + OFF_W2, eb2 + l * 96, agg16);
        const _Float16* wnext = wT + WT_LAYER(l < 2 ? l + 1 : 0);
        k_nodeab<<<dim3(782), dim3(256), 0, stream>>>(h16, agg16,
            wl + OFF_NW1, nb1 + l * 96, wl + OFF_NW2, nb2 + l * 96,
            wnext + OFF_W1AB, A16, B16, batch, pooled, (l < 2) ? 1 : 0);
    }
    k_final<<<dim3(50), dim3(64), 0, stream>>>(pooled, batch, Wl, bl, out);
}

// Round 20
// 618.365 us; speedup vs baseline: 1.1069x; 1.1069x over previous
//
#include <hip/hip_runtime.h>
#include <hip/hip_fp16.h>

#define Nn 50000
#define Ee 800000
#define FIN 32
#define EDIM 16
#define Bb 50
#define SPX 6250   // 16-edge spans per XCD (50000 total / 8)

typedef _Float16 half8 __attribute__((ext_vector_type(8)));
typedef float floatx4 __attribute__((ext_vector_type(4)));

// wT (f16 transposed weights) offsets, in f16 elements
#define OFF_WeT 0
#define WT_LAYER(l) (3072 + (l) * 58368)
#define OFF_W1AB 0        // [192][96]
#define OFF_W1C  18432    // [96][32]
#define OFF_W2   21504    // [96][96]
#define OFF_NW1  30720    // [96][192]
#define OFF_NW2  49152    // [96][96]
#define WT_TOTAL 178176

// f16-native silu: v_exp_f16/v_rcp_f16, no f32 converts
__device__ __forceinline__ _Float16 silu_h32(float xf) {
    __half x = __float2half(xf);
    __half e = hexp(__hneg(x));
    __half r = hrcp(__hadd(__float2half(1.0f), e));
    __half res = __hmul(x, r);
    return __builtin_bit_cast(_Float16, res);
}

__device__ __forceinline__ half8 silu_h8(half8 v) {
    half8 out;
    __half2* vp = (__half2*)&v;
    __half2* op = (__half2*)&out;
    const __half2 one = __float2half2_rn(1.0f);
    #pragma unroll
    for (int i = 0; i < 4; i++) {
        __half2 x = vp[i];
        __half2 e = h2exp(__hneg2(x));
        __half2 r = h2rcp(__hadd2(one, e));
        op[i] = __hmul2(x, r);
    }
    return out;
}

__device__ __forceinline__ int lower_bound_i(const int* a, int n, int v) {
    int lo = 0, hi = n;
    while (lo < hi) { int m = (lo + hi) >> 1; if (a[m] < v) lo = m + 1; else hi = m; }
    return lo;
}

__device__ __forceinline__ half8 ldg_h8(const _Float16* p) {
    return *(const half8*)p;
}

__device__ __forceinline__ half8 h8_zero() {
    half8 z;
    #pragma unroll
    for (int j = 0; j < 8; j++) z[j] = (_Float16)0.f;
    return z;
}

// ---------------- weight transpose+cast to f16 ----------------
__global__ void k_prepw(const float* __restrict__ We, const float* __restrict__ eW1,
                        const float* __restrict__ eW2, const float* __restrict__ nW1,
                        const float* __restrict__ nW2, _Float16* __restrict__ wT) {
    int idx = blockIdx.x * 256 + threadIdx.x;
    if (idx >= WT_TOTAL) return;
    float v;
    if (idx < 3072) {                       // WeT[n][k]
        int n = idx >> 5, k = idx & 31;
        v = We[k * 96 + n];
    } else {
        int j = idx - 3072;
        int l = j / 58368, r = j % 58368;
        const float* eW1l = eW1 + l * 209 * 96;
        if (r < 18432) {                    // W1abT[n][k]
            int n = r / 96, k = r % 96;
            v = (n < 96) ? eW1l[k * 96 + n] : eW1l[(96 + k) * 96 + (n - 96)];
        } else if (r < 21504) {             // W1cT[n][k]
            int r2 = r - 18432;
            int n = r2 >> 5, k = r2 & 31;
            v = (k < 16) ? eW1l[(193 + k) * 96 + n]
              : (k == 16) ? eW1l[192 * 96 + n] : 0.f;
        } else if (r < 30720) {             // W2T[n][k]
            int r2 = r - 21504;
            int n = r2 / 96, k = r2 % 96;
            v = eW2[l * 9216 + k * 96 + n];
        } else if (r < 49152) {             // nW1T[n][k]
            int r2 = r - 30720;
            int n = r2 / 192, k = r2 % 192;
            v = nW1[l * 18432 + k * 96 + n];
        } else {                            // nW2T[n][k]
            int r2 = r - 49152;
            int n = r2 / 96, k = r2 % 96;
            v = nW2[l * 9216 + k * 96 + n];
        }
    }
    wT[idx] = (_Float16)v;
}

// ---------------- edge prep: dst histogram only ----------------
__global__ void k_prep(const int* __restrict__ ei, int* __restrict__ counts) {
    int e = blockIdx.x * 256 + threadIdx.x;
    if (e >= Ee) return;
    atomicAdd(&counts[ei[Ee + e]], 1);
}

// ---------------- two-level exclusive scan -> rowstart ----------------
__global__ void k_scanA(const int* __restrict__ counts, int* __restrict__ rowstart,
                        int* __restrict__ bsums) {
    __shared__ int s[256];
    int b = blockIdx.x, t = threadIdx.x, i = b * 256 + t;
    int v = (i < Nn) ? counts[i] : 0;
    s[t] = v;
    __syncthreads();
    for (int off = 1; off < 256; off <<= 1) {
        int add = (t >= off) ? s[t - off] : 0;
        __syncthreads();
        s[t] += add;
        __syncthreads();
    }
    if (i < Nn) rowstart[i + 1] = s[t];
    if (t == 255) bsums[b] = s[255];
}

__global__ void k_scanB(int* __restrict__ bsums, int nb) {
    __shared__ int s[256];
    int t = threadIdx.x;
    int v = (t < nb) ? bsums[t] : 0;
    s[t] = v;
    __syncthreads();
    for (int off = 1; off < 256; off <<= 1) {
        int add = (t >= off) ? s[t - off] : 0;
        __syncthreads();
        s[t] += add;
        __syncthreads();
    }
    if (t < nb) bsums[t] = s[t] - v;
}

__global__ void k_scanC(int* __restrict__ rowstart, const int* __restrict__ bsums) {
    int b = blockIdx.x, t = threadIdx.x, i = b * 256 + t;
    if (i < Nn) rowstart[i + 1] += bsums[b];
    if (i == 0 && b == 0) rowstart[0] = 0;
}

// ---------------- CSR fill pass 1: scatter perm only (4 B/edge) ----------------
__global__ void k_fill1(const int* __restrict__ ei, const int* __restrict__ rowstart,
                        int* __restrict__ cur, int* __restrict__ perm) {
    int e = blockIdx.x * 256 + threadIdx.x;
    if (e >= Ee) return;
    int d = ei[Ee + e];
    int slot = rowstart[d] + atomicAdd(&cur[d], 1);
    perm[slot] = e;
}

// ---------------- CSR fill pass 2: gather (random reads), coalesced writes -----
__global__ void k_fill2(const int* __restrict__ perm, const int* __restrict__ ei,
                        const float* __restrict__ ea, const float* __restrict__ pos,
                        int* __restrict__ srcs_p, int* __restrict__ dsts_p,
                        _Float16* __restrict__ eap16, _Float16* __restrict__ d2h) {
    int slot = blockIdx.x * 256 + threadIdx.x;
    if (slot >= Ee) return;
    int e = perm[slot];
    int s = ei[e], d = ei[Ee + e];
    srcs_p[slot] = s;
    dsts_p[slot] = d;
    float dx = pos[s * 3 + 0] - pos[d * 3 + 0];
    float dy = pos[s * 3 + 1] - pos[d * 3 + 1];
    float dz = pos[s * 3 + 2] - pos[d * 3 + 2];
    float dv = dx * dx + dy * dy + dz * dz;
    const float4* ea4 = (const float4*)ea;
    float4 q0 = ea4[e * 4 + 0], q1 = ea4[e * 4 + 1];
    float4 q2 = ea4[e * 4 + 2], q3 = ea4[e * 4 + 3];
    half8 c0, c1;
    c0[0]=(_Float16)q0.x; c0[1]=(_Float16)q0.y; c0[2]=(_Float16)q0.z; c0[3]=(_Float16)q0.w;
    c0[4]=(_Float16)q1.x; c0[5]=(_Float16)q1.y; c0[6]=(_Float16)q1.z; c0[7]=(_Float16)q1.w;
    c1[0]=(_Float16)q2.x; c1[1]=(_Float16)q2.y; c1[2]=(_Float16)q2.z; c1[3]=(_Float16)q2.w;
    c1[4]=(_Float16)q3.x; c1[5]=(_Float16)q3.y; c1[6]=(_Float16)q3.z; c1[7]=(_Float16)q3.w;
    half8* dst8 = (half8*)(eap16 + (size_t)slot * 16);
    dst8[0] = c0; dst8[1] = c1;
    d2h[slot] = (_Float16)dv;
}

// ---------------- encoder + A/B(l0) + zero agg (f16) ----------------
__global__ __launch_bounds__(256, 4)
void k_encab(const float* __restrict__ x, const _Float16* __restrict__ WeT,
             const float* __restrict__ be, const _Float16* __restrict__ W1abT,
             _Float16* __restrict__ h16, _Float16* __restrict__ A16,
             _Float16* __restrict__ B16, _Float16* __restrict__ agg16) {
    __shared__ _Float16 x16[64][40];
    __shared__ _Float16 hs[64][104];
    int t = threadIdx.x;
    int n0 = blockIdx.x * 64;
    for (int i = t; i < 64 * 32; i += 256) {
        int nl = i >> 5, k = i & 31;
        int n = n0 + nl;
        x16[nl][k] = (_Float16)((n < Nn) ? x[n * FIN + k] : 0.f);
    }
    __syncthreads();
    int lane = t & 63, quad = lane >> 4, lm = lane & 15, w = t >> 6;
    half8 af = *(const half8*)&x16[w * 16 + lm][quad * 8];
    #pragma unroll
    for (int nt = 0; nt < 6; nt++) {
        int col = nt * 16 + lm;
        float b = be[col];
        floatx4 acc = {b, b, b, b};
        half8 bf = ldg_h8(WeT + col * 32 + quad * 8);
        acc = __builtin_amdgcn_mfma_f32_16x16x32_f16(af, bf, acc, 0, 0, 0);
        #pragma unroll
        for (int r = 0; r < 4; r++)
            hs[w * 16 + quad * 4 + r][col] = (_Float16)acc[r];
    }
    __syncthreads();
    // coalesced h16 write + zero agg (f16)
    #pragma unroll
    for (int i = 0; i < 3; i++) {
        int ci = t + 256 * i;
        int el = ci / 12, c0 = (ci % 12) * 8;
        int n = n0 + el;
        if (n < Nn) {
            *(half8*)(h16 + n * 96 + c0) = *(half8*)&hs[el][c0];
            *(half8*)(agg16 + n * 96 + c0) = h8_zero();
        }
    }
    // A/B for layer 0
    half8 af3[3];
    #pragma unroll
    for (int kt = 0; kt < 3; kt++)
        af3[kt] = *(const half8*)&hs[w * 16 + lm][kt * 32 + quad * 8];
    #pragma unroll
    for (int nt = 0; nt < 12; nt++) {
        int col = nt * 16 + lm;
        floatx4 acc = {0.f, 0.f, 0.f, 0.f};
        #pragma unroll
        for (int kt = 0; kt < 3; kt++) {
            half8 bf = ldg_h8(W1abT + col * 96 + kt * 32 + quad * 8);
            acc = __builtin_amdgcn_mfma_f32_16x16x32_f16(af3[kt], bf, acc, 0, 0, 0);
        }
        #pragma unroll
        for (int r = 0; r < 4; r++) {
            int n = n0 + w * 16 + quad * 4 + r;
            if (n < Nn) {
                if (col < 96) A16[n * 96 + col] = (_Float16)acc[r];
                else          B16[n * 96 + col - 96] = (_Float16)acc[r];
            }
        }
    }
}

// ---------------- per-layer edge kernel: wave-autonomous (r18 config) ----------
// LDS: u16 13312 + W2f 18432 + W1f 6144 + ss/ds 512 = 38400 B -> 4 blocks/CU.
// 4 blocks/CU is a hard wall: VGPR-capping spills (r7/r12), LDS-shrink doesn't
// gain residency due to allocation granularity and tails the grid (r19).
__global__ __launch_bounds__(256, 4)
void k_edge(const _Float16* __restrict__ A16, const _Float16* __restrict__ B16,
            const _Float16* __restrict__ eap16, const _Float16* __restrict__ d2h,
            const int* __restrict__ srcs_p, const int* __restrict__ dsts_p,
            const _Float16* __restrict__ W1cT, const float* __restrict__ eb1l,
            const _Float16* __restrict__ W2T, const float* __restrict__ eb2l,
            _Float16* __restrict__ agg16) {
    __shared__ _Float16 u16[64][104];       // wave-private 16-row quarters
    __shared__ _Float16 W2f[18 * 64 * 8];   // fragment-major: [nt*3+kt][lane][8]
    __shared__ _Float16 W1f[6 * 64 * 8];    // fragment-major: [nt][lane][8]
    __shared__ int ss_s[4][16], ds_s[4][16];

    int t = threadIdx.x;
    int lane = t & 63, quad = lane >> 4, lm = lane & 15, w = t >> 6;

    // one-time fragment-major weight staging
    for (int f = w; f < 18; f += 4) {
        int nt = f / 3, kt = f % 3;
        half8 v = ldg_h8(W2T + (nt * 16 + lm) * 96 + kt * 32 + quad * 8);
        *(half8*)&W2f[(f * 64 + lane) * 8] = v;
    }
    for (int f = w; f < 6; f += 4) {
        half8 v = ldg_h8(W1cT + (f * 16 + lm) * 32 + quad * 8);
        *(half8*)&W1f[(f * 64 + lane) * 8] = v;
    }
    float eb1v[6], eb2v[6];
    #pragma unroll
    for (int nt = 0; nt < 6; nt++) {
        eb1v[nt] = eb1l[nt * 16 + lm];
        eb2v[nt] = eb2l[nt * 16 + lm];
    }
    __syncthreads();   // the only barrier

    int xcd = blockIdx.x & 7, ib = blockIdx.x >> 3;   // 128 blocks/XCD
    int slot = ib * 4 + w;                            // 512 wave slots per XCD
    for (int s = slot; s < SPX; s += 512) {
        int e0 = (xcd * SPX + s) * 16;
        // ---- prefetch edge data (global only) ----
        half8 af1;
        if (quad == 0)      af1 = ldg_h8(eap16 + (size_t)(e0 + lm) * 16);
        else if (quad == 1) af1 = ldg_h8(eap16 + (size_t)(e0 + lm) * 16 + 8);
        else { af1 = h8_zero(); if (quad == 2) af1[0] = d2h[e0 + lm]; }
        if (lane < 16) {
            ss_s[w][lane] = srcs_p[e0 + lane];
            ds_s[w][lane] = dsts_p[e0 + lane];
        }
        // ---- phase 1a: pre = eb1 + [ea|d2]@W1c -> u16 (C-layout, own rows) ----
        #pragma unroll
        for (int nt = 0; nt < 6; nt++) {
            floatx4 acc = {eb1v[nt], eb1v[nt], eb1v[nt], eb1v[nt]};
            half8 bf = *(const half8*)&W1f[(nt * 64 + lane) * 8];
            acc = __builtin_amdgcn_mfma_f32_16x16x32_f16(af1, bf, acc, 0, 0, 0);
            #pragma unroll
            for (int r = 0; r < 4; r++)
                u16[w * 16 + quad * 4 + r][nt * 16 + lm] = (_Float16)acc[r];
        }
        // ---- phase 1b: u = silu(pre + A[src] + B[dst]); packed f16 silu ----
        #pragma unroll
        for (int i = 0; i < 3; i++) {
            int ci = lane + 64 * i;          // 192 chunks = 16 rows x 12
            int el = ci / 12, c0 = (ci % 12) * 8;
            half8 av = ldg_h8(A16 + ss_s[w][el] * 96 + c0);
            half8 bv = ldg_h8(B16 + ds_s[w][el] * 96 + c0);
            half8 pv = *(half8*)&u16[w * 16 + el][c0];
            *(half8*)&u16[w * 16 + el][c0] = silu_h8(pv + av + bv);
        }
        // ---- phase 2: m = silu(u @ W2 + eb2) -> u16 (own rows) ----
        half8 af2[3];
        #pragma unroll
        for (int kt = 0; kt < 3; kt++)
            af2[kt] = *(const half8*)&u16[w * 16 + lm][kt * 32 + quad * 8];
        #pragma unroll
        for (int nt = 0; nt < 6; nt++) {
            floatx4 acc = {eb2v[nt], eb2v[nt], eb2v[nt], eb2v[nt]};
            #pragma unroll
            for (int kt = 0; kt < 3; kt++) {
                half8 bf = *(const half8*)&W2f[((nt * 3 + kt) * 64 + lane) * 8];
                acc = __builtin_amdgcn_mfma_f32_16x16x32_f16(af2[kt], bf, acc, 0, 0, 0);
            }
            #pragma unroll
            for (int r = 0; r < 4; r++)
                u16[w * 16 + quad * 4 + r][nt * 16 + lm] = silu_h32(acc[r]);
        }
        // ---- segmented reduction: 48-lane column-pair scan, packed atomics ----
        if (lane < 48) {
            __half2* aggp = (__half2*)agg16;
            float run0 = 0.f, run1 = 0.f;
            int cd = ds_s[w][0];
            #pragma unroll
            for (int e = 0; e < 16; e++) {
                int dn = ds_s[w][e];
                if (dn != cd) {
                    unsafeAtomicAdd(&aggp[cd * 48 + lane], __floats2half2_rn(run0, run1));
                    run0 = 0.f; run1 = 0.f; cd = dn;
                }
                __half2 v = *(const __half2*)&u16[w * 16 + e][lane * 2];
                float2 vf = __half22float2(v);
                run0 += vf.x; run1 += vf.y;
            }
            unsafeAtomicAdd(&aggp[cd * 48 + lane], __floats2half2_rn(run0, run1));
        }
    }
}

// ---------------- node MLP + residual + next-layer A/B (or fused pooling) -----
__global__ __launch_bounds__(256, 4)
void k_nodeab(_Float16* __restrict__ h16, _Float16* __restrict__ agg16,
              const _Float16* __restrict__ nW1T, const float* __restrict__ nb1l,
              const _Float16* __restrict__ nW2T, const float* __restrict__ nb2l,
              const _Float16* __restrict__ W1abT, _Float16* __restrict__ A16,
              _Float16* __restrict__ B16, const int* __restrict__ batch,
              float* __restrict__ pooled, int do_ab) {
    __shared__ _Float16 in16[64][200];   // [h | agg] f16
    __shared__ _Float16 t116[64][104];
    __shared__ int gb_s[64];
    int t = threadIdx.x, n0 = blockIdx.x * 64;
    #pragma unroll
    for (int i = 0; i < 3; i++) {
        int ci = t + 256 * i;
        int el = ci / 12, c0 = (ci % 12) * 8;
        int n = n0 + el;
        half8 hv = h8_zero();
        half8 av = h8_zero();
        if (n < Nn) {
            hv = ldg_h8(h16 + n * 96 + c0);
            av = ldg_h8(agg16 + n * 96 + c0);
        }
        *(half8*)&in16[el][c0] = hv;
        *(half8*)&in16[el][96 + c0] = av;
    }
    if (!do_ab && t < 64) {
        int n = n0 + t;
        gb_s[t] = (n < Nn) ? batch[n] : -1;
    }
    __syncthreads();
    int lane = t & 63, quad = lane >> 4, lm = lane & 15, w = t >> 6;
    half8 af[6];
    #pragma unroll
    for (int kt = 0; kt < 6; kt++)
        af[kt] = *(const half8*)&in16[w * 16 + lm][kt * 32 + quad * 8];
    #pragma unroll
    for (int nt = 0; nt < 6; nt++) {
        int col = nt * 16 + lm;
        float b = nb1l[col];
        floatx4 acc = {b, b, b, b};
        #pragma unroll
        for (int kt = 0; kt < 6; kt++) {
            half8 bf = ldg_h8(nW1T + col * 192 + kt * 32 + quad * 8);
            acc = __builtin_amdgcn_mfma_f32_16x16x32_f16(af[kt], bf, acc, 0, 0, 0);
        }
        #pragma unroll
        for (int r = 0; r < 4; r++)
            t116[w * 16 + quad * 4 + r][col] = silu_h32(acc[r]);
    }
    // t116 rows are wave-private: same-wave LDS ops are ordered -> no barrier.
    half8 af2[3];
    #pragma unroll
    for (int kt = 0; kt < 3; kt++)
        af2[kt] = *(const half8*)&t116[w * 16 + lm][kt * 32 + quad * 8];
    #pragma unroll
    for (int nt = 0; nt < 6; nt++) {
        int col = nt * 16 + lm;
        float b = nb2l[col];
        floatx4 acc = {b, b, b, b};
        #pragma unroll
        for (int kt = 0; kt < 3; kt++) {
            half8 bf = ldg_h8(nW2T + col * 96 + kt * 32 + quad * 8);
            acc = __builtin_amdgcn_mfma_f32_16x16x32_f16(af2[kt], bf, acc, 0, 0, 0);
        }
        // residual: h_new = h_old + upd (same owner thread)
        #pragma unroll
        for (int r = 0; r < 4; r++) {
            int row = w * 16 + quad * 4 + r;
            float hnew = (float)in16[row][col] + acc[r];
            in16[row][col] = (_Float16)hnew;
        }
    }
    __syncthreads();   // in16 read cross-wave below
    if (!do_ab) {
        // fused global_mean_pool numerator: segmented scan by graph id.
        if (t < 96) {
            float run = 0.f;
            int cd = gb_s[0];
            for (int e = 0; e < 64; e++) {
                int g = gb_s[e];
                if (g != cd) {
                    if (cd >= 0) atomicAdd(&pooled[cd * 96 + t], run);
                    run = 0.f; cd = g;
                }
                run += (float)in16[e][t];
            }
            if (cd >= 0) atomicAdd(&pooled[cd * 96 + t], run);
        }
        return;
    }
    // coalesced h16 write + next-layer A/B + agg rezero (f16)
    #pragma unroll
    for (int i = 0; i < 3; i++) {
        int ci = t + 256 * i;
        int el = ci / 12, c0 = (ci % 12) * 8;
        int n = n0 + el;
        if (n < Nn) {
            *(half8*)(h16 + n * 96 + c0) = *(half8*)&in16[el][c0];
            *(half8*)(agg16 + n * 96 + c0) = h8_zero();
        }
    }
    half8 af3[3];
    #pragma unroll
    for (int kt = 0; kt < 3; kt++)
        af3[kt] = *(const half8*)&in16[w * 16 + lm][kt * 32 + quad * 8];
    #pragma unroll
    for (int nt = 0; nt < 12; nt++) {
        int col = nt * 16 + lm;
        floatx4 acc = {0.f, 0.f, 0.f, 0.f};
        #pragma unroll
        for (int kt = 0; kt < 3; kt++) {
            half8 bf = ldg_h8(W1abT + col * 96 + kt * 32 + quad * 8);
            acc = __builtin_amdgcn_mfma_f32_16x16x32_f16(af3[kt], bf, acc, 0, 0, 0);
        }
        #pragma unroll
        for (int r = 0; r < 4; r++) {
            int n = n0 + w * 16 + quad * 4 + r;
            if (n < Nn) {
                if (col < 96) A16[n * 96 + col] = (_Float16)acc[r];
                else          B16[n * 96 + col - 96] = (_Float16)acc[r];
            }
        }
    }
}

// ---------------- final head ----------------
__global__ void k_final(const float* __restrict__ pooled, const int* __restrict__ batch,
                        const float* __restrict__ Wl, const float* __restrict__ bl,
                        float* __restrict__ out) {
    int g = blockIdx.x, lane = threadIdx.x;
    int start = lower_bound_i(batch, Nn, g);
    int end   = lower_bound_i(batch, Nn, g + 1);
    int cnt = end - start; if (cnt < 1) cnt = 1;
    float v = 0.f;
    for (int j = lane; j < 96; j += 64) v += pooled[g * 96 + j] * Wl[j];
    #pragma unroll
    for (int off = 32; off > 0; off >>= 1) v += __shfl_down(v, off);
    if (lane == 0) out[g] = v / (float)cnt + bl[0];
}

extern "C" void kernel_launch(void* const* d_in, const int* in_sizes, int n_in,
                              void* d_out, int out_size, void* d_ws, size_t ws_size,
                              hipStream_t stream) {
    const float* x     = (const float*)d_in[0];
    const float* pos   = (const float*)d_in[1];
    const int*   ei    = (const int*)d_in[2];
    const float* ea    = (const float*)d_in[3];
    const int*   batch = (const int*)d_in[4];
    const float* We    = (const float*)d_in[5];
    const float* be    = (const float*)d_in[6];
    const float* eW1   = (const float*)d_in[7];
    const float* eb1   = (const float*)d_in[8];
    const float* eW2   = (const float*)d_in[9];
    const float* eb2   = (const float*)d_in[10];
    const float* nW1   = (const float*)d_in[11];
    const float* nb1   = (const float*)d_in[12];
    const float* nW2   = (const float*)d_in[13];
    const float* nb2   = (const float*)d_in[14];
    const float* Wl    = (const float*)d_in[15];
    const float* bl    = (const float*)d_in[16];
    float* out = (float*)d_out;

    float* ws = (float*)d_ws;
    _Float16* h16    = (_Float16*)(ws);                 // 4.8M halfs
    _Float16* A16    = (_Float16*)(ws + 2400000);       // 4.8M halfs
    _Float16* B16    = (_Float16*)(ws + 4800000);       // 4.8M halfs
    _Float16* agg16  = (_Float16*)(ws + 7200000);       // 4.8M halfs
    float*    pooled = ws + 9600000;                    // 4800
    int*      counts   = (int*)(ws + 9604800);          // 50000
    int*      cur      = (int*)(ws + 9654800);          // 50000
    int*      rowstart = (int*)(ws + 9704800);          // 50001
    int*      bsums    = (int*)(ws + 9754816);          // 256
    int*      srcs_p   = (int*)(ws + 9755072);          // 800000
    int*      dsts_p   = (int*)(ws + 10555072);         // 800000
    int*      perm     = (int*)(ws + 11355072);         // 800000
    _Float16* eap16    = (_Float16*)(ws + 12155072);    // 12.8M halfs
    _Float16* d2h      = (_Float16*)(ws + 18555072);    // 0.8M halfs
    _Float16* wT       = (_Float16*)(ws + 18955072);    // 178176 halfs

    hipMemsetAsync(counts, 0, 2 * 50000 * sizeof(int), stream);   // counts + cur
    hipMemsetAsync(pooled, 0, Bb * 96 * sizeof(float), stream);

    k_prepw<<<dim3(696), dim3(256), 0, stream>>>(We, eW1, eW2, nW1, nW2, wT);
    k_prep<<<dim3(3125), dim3(256), 0, stream>>>(ei, counts);
    k_scanA<<<dim3(196), dim3(256), 0, stream>>>(counts, rowstart, bsums);
    k_scanB<<<dim3(1), dim3(256), 0, stream>>>(bsums, 196);
    k_scanC<<<dim3(196), dim3(256), 0, stream>>>(rowstart, bsums);
    k_fill1<<<dim3(3125), dim3(256), 0, stream>>>(ei, rowstart, cur, perm);
    k_fill2<<<dim3(3125), dim3(256), 0, stream>>>(perm, ei, ea, pos,
                                                  srcs_p, dsts_p, eap16, d2h);
    k_encab<<<dim3(782), dim3(256), 0, stream>>>(x, wT + OFF_WeT, be,
        wT + WT_LAYER(0) + OFF_W1AB, h16, A16, B16, agg16);

    for (int l = 0; l < 3; l++) {
        const _Float16* wl = wT + WT_LAYER(l);
        k_edge<<<dim3(1024), dim3(256), 0, stream>>>(A16, B16, eap16, d2h,
            srcs_p, dsts_p, wl + OFF_W1C, eb1 + l * 96, wl + OFF_W2, eb2 + l * 96, agg16);
        const _Float16* wnext = wT + WT_LAYER(l < 2 ? l + 1 : 0);
        k_nodeab<<<dim3(782), dim3(256), 0, stream>>>(h16, agg16,
            wl + OFF_NW1, nb1 + l * 96, wl + OFF_NW2, nb2 + l * 96,
            wnext + OFF_W1AB, A16, B16, batch, pooled, (l < 2) ? 1 : 0);
    }
    k_final<<<dim3(50), dim3(64), 0, stream>>>(pooled, batch, Wl, bl, out);
}